// Round 9
// baseline (455.867 us; speedup 1.0000x reference)
//
#include <hip/hip_runtime.h>
#include <cmath>

#define NN 8192

typedef _Float16 half8 __attribute__((ext_vector_type(8)));
typedef float floatx4 __attribute__((ext_vector_type(4)));
typedef unsigned int uint;

// ---------------------------------------------------------------------------
// h_kernel<L2>: H[ch] = X @ w_ch, output fp16 in MFMA B-fragment order:
//   Hfrag[ch][t][tile][lane][elem], t=j>>5, lane=(n&15)|(((j&31)>>3)<<4),
//   tile=n>>4, elem=j&7.
// L2=0: X = V (f32 [8192,32]).  L2=1: X = relu(sum_{c<8} Zpart[c] + gbias).
// Grid dim3(128,3): blockIdx.y = channel, block owns 64 rows of X.
// ---------------------------------------------------------------------------
template <int L2>
__global__ __launch_bounds__(256) void h_kernel(
    const float* __restrict__ X, const float* __restrict__ w1,
    const float* __restrict__ w2, const float* __restrict__ w3,
    const float* __restrict__ gbias, _Float16* __restrict__ Hfrag) {
  __shared__ float wl[32][32];   // wl[d][n]
  __shared__ float Xs[64][32];
  const int tid = threadIdx.x;
  const int ch = blockIdx.y;
  const float* wsrc = (ch == 0) ? w1 : (ch == 1) ? w2 : w3;
  for (int i = tid; i < 1024; i += 256) ((float*)wl)[i] = wsrc[i];
  const size_t base = (size_t)blockIdx.x * 2048 + tid * 8;
  if (L2 == 0) {
    float4 x0 = ((const float4*)(X + base))[0];
    float4 x1 = ((const float4*)(X + base))[1];
    *((float4*)(&Xs[0][0] + tid * 8)) = x0;
    *((float4*)(&Xs[0][0] + tid * 8 + 4)) = x1;
  } else {
    float4 s0 = {0.f, 0.f, 0.f, 0.f}, s1 = {0.f, 0.f, 0.f, 0.f};
#pragma unroll
    for (int c = 0; c < 8; ++c) {
      const float4* p = (const float4*)(X + (size_t)c * NN * 32 + base);
      float4 a = p[0], b = p[1];
      s0.x += a.x; s0.y += a.y; s0.z += a.z; s0.w += a.w;
      s1.x += b.x; s1.y += b.y; s1.z += b.z; s1.w += b.w;
    }
    const int c0 = (tid * 8) & 31;
    const float4 b0 = *(const float4*)(gbias + c0);
    const float4 b1 = *(const float4*)(gbias + c0 + 4);
    s0.x += b0.x; s0.y += b0.y; s0.z += b0.z; s0.w += b0.w;
    s1.x += b1.x; s1.y += b1.y; s1.z += b1.z; s1.w += b1.w;
    s0.x = s0.x > 0.f ? s0.x : 0.f; s0.y = s0.y > 0.f ? s0.y : 0.f;
    s0.z = s0.z > 0.f ? s0.z : 0.f; s0.w = s0.w > 0.f ? s0.w : 0.f;
    s1.x = s1.x > 0.f ? s1.x : 0.f; s1.y = s1.y > 0.f ? s1.y : 0.f;
    s1.z = s1.z > 0.f ? s1.z : 0.f; s1.w = s1.w > 0.f ? s1.w : 0.f;
    *((float4*)(&Xs[0][0] + tid * 8)) = s0;
    *((float4*)(&Xs[0][0] + tid * 8 + 4)) = s1;
  }
  __syncthreads();
  const int n = tid & 31, jb = tid >> 5;
  const int j0 = blockIdx.x * 64 + jb * 8;
  const int t = j0 >> 5;
  const int lane = (n & 15) | (((j0 & 31) >> 3) << 4);
  const int tile = n >> 4;
  half8 hv;
#pragma unroll
  for (int jj = 0; jj < 8; ++jj) {
    const float4* xr = (const float4*)(&Xs[jb * 8 + jj][0]);
    float acc = 0.f;
#pragma unroll
    for (int d4 = 0; d4 < 8; ++d4) {
      float4 x = xr[d4];
      acc += x.x * wl[d4 * 4 + 0][n];
      acc += x.y * wl[d4 * 4 + 1][n];
      acc += x.z * wl[d4 * 4 + 2][n];
      acc += x.w * wl[d4 * 4 + 3][n];
    }
    hv[jj] = (_Float16)acc;
  }
  size_t idx = ((((size_t)ch * 256 + t) * 2 + tile) * 64 + lane) * 8;
  *(half8*)(Hfrag + idx) = hv;
}

// ---------------------------------------------------------------------------
// pack_kernel (verified R4/R5 layout): pure streaming pass over adj. Block
// (rg32,c) reads rows rg32*32..+32, j c*1024..+1024 with contiguous dwordx4
// loads, packs 2-bit codes into an 8KB LDS tile in MFMA A-fragment consume
// order, dumps it to packed_g as one contiguous 8KB run:
//   dword[tg*256 + ((r&15)+16*qt)*4 + t4], byte (r>>4)*2+ih, bits 2d
//   <- adj[rg32*32+r][c*1024 + (tg*4+t4)*32 + qt*8 + ih*4 + d]
// Grid 2048 = (rg32:256) x (c:8), 8 blocks/CU.
// ---------------------------------------------------------------------------
__global__ __launch_bounds__(256, 8) void pack_kernel(
    const int* __restrict__ adj, uint* __restrict__ packed_g) {
  __shared__ uint ptile[2048];
  const int tid = threadIdx.x;
  const int rg = blockIdx.x >> 3, c = blockIdx.x & 7;
  const int tg = tid >> 5;            // j-tile-group of 4 tiles
  const int qt = (tid >> 1) & 3;      // quad within tile
  const int t4 = (tid >> 3) & 3;      // tile within group
  const int ih = tid & 1;             // 4-j half of the 8-j quad
  const int byte_base = tg * 1024 + qt * 256 + t4 * 4 + ih;
  unsigned char* pb = (unsigned char*)ptile;
  const size_t gofs = (size_t)rg * 32 * NN + c * 1024 + tid * 4;
#pragma unroll
  for (int r0 = 0; r0 < 32; r0 += 8) {
    int4 a[8];
#pragma unroll
    for (int rr = 0; rr < 8; ++rr)
      a[rr] = *(const int4*)(adj + gofs + (size_t)(r0 + rr) * NN);
#pragma unroll
    for (int rr = 0; rr < 8; ++rr) {
      const int r = r0 + rr;
      const uint b = (uint)(a[rr].x & 3) | ((uint)(a[rr].y & 3) << 2) |
                     ((uint)(a[rr].z & 3) << 4) | ((uint)(a[rr].w & 3) << 6);
      pb[byte_base + (r & 15) * 16 + (r >> 4) * 2] = (unsigned char)b;
    }
  }
  __syncthreads();
  uint* pg = packed_g + (size_t)blockIdx.x * 2048;
  *(uint4*)(pg + tid * 8) = *(const uint4*)(ptile + tid * 8);
  *(uint4*)(pg + tid * 8 + 4) = *(const uint4*)(ptile + tid * 8 + 4);
}

// ---------------------------------------------------------------------------
// agg_kernel (M=64 per wave, both layers): block (rg64,c) = 64 rows x 1024 j.
// Grid 128x8 = 1024 blocks = exactly 4 blocks/CU at (256,4). Wave w owns
// k-tiles w*8..+7; mask words for the two 32-row units come from the
// consume-order packed buffer (4 coalesced dwordx4 loads -> mkA/mkB; uint =
// rows g*16..+15 in low16, +16..+31 in high16). Per k-tile: prefetch next
// tile's 6 Hf B-fragments, then per channel build 4 A-frags (one per 16-row
// group) and issue 8 MFMAs -> 24 MFMA/tile, Hf bytes/row halved vs M=32.
// Epilogue: 4-wave LDS reduce, wave g writes row-group g. Raw partials ->
// Zpart[c][row][32] (C/D layout verified: col=lane&15, row=(lane>>4)*4+reg).
// ---------------------------------------------------------------------------
__global__ __launch_bounds__(256, 4) void agg_kernel(
    const uint* __restrict__ packed_g, const half8* __restrict__ Hf,
    float* __restrict__ Zpart) {
  __shared__ float red[4][8][64][4];  // 32 KB
  const int tid = threadIdx.x;
  const int rg = blockIdx.x >> 3, c = blockIdx.x & 7;  // rg64: 0..127
  const int w = tid >> 6, lane = tid & 63;
  const int m = lane & 15, q = lane >> 4;
  // mask words (consume-order): tile units rg*2 (rows +0..31), rg*2+1 (+32..63)
  const uint* pgA =
      packed_g + ((size_t)(rg * 2) * 8 + c) * 2048 + (w * 2) * 256 + lane * 4;
  const uint* pgB =
      packed_g + ((size_t)(rg * 2 + 1) * 8 + c) * 2048 + (w * 2) * 256 + lane * 4;
  uint mkA[8], mkB[8];
  *(uint4*)(mkA) = *(const uint4*)(pgA);
  *(uint4*)(mkA + 4) = *(const uint4*)(pgA + 256);
  *(uint4*)(mkB) = *(const uint4*)(pgB);
  *(uint4*)(mkB + 4) = *(const uint4*)(pgB + 256);
  const half8* hp = Hf + (size_t)(c * 32 + w * 8) * 128 + lane;
  // prologue: tile 0 fragments
  half8 b00 = hp[0],     b01 = hp[64];
  half8 b10 = hp[32768], b11 = hp[32768 + 64];
  half8 b20 = hp[65536], b21 = hp[65536 + 64];
  floatx4 acc[4][2];
#pragma unroll
  for (int g = 0; g < 4; ++g)
#pragma unroll
    for (int h = 0; h < 2; ++h) acc[g][h] = (floatx4){0.f, 0.f, 0.f, 0.f};
#pragma unroll
  for (int tl = 0; tl < 8; ++tl) {
    half8 n00, n01, n10, n11, n20, n21;
    if (tl < 7) {  // prefetch next tile while we chew on this one
      const half8* np = hp + (tl + 1) * 128;
      n00 = np[0];     n01 = np[64];
      n10 = np[32768]; n11 = np[32768 + 64];
      n20 = np[65536]; n21 = np[65536 + 64];
    }
    const uint pkA = mkA[tl], pkB = mkB[tl];
    // channel 1
    {
      half8 a0, a1, a2, a3;
#pragma unroll
      for (int i = 0; i < 8; ++i) {
        a0[i] = (((pkA >> (2 * i)) & 3) == 1) ? (_Float16)1.f : (_Float16)0.f;
        a1[i] = (((pkA >> (16 + 2 * i)) & 3) == 1) ? (_Float16)1.f : (_Float16)0.f;
        a2[i] = (((pkB >> (2 * i)) & 3) == 1) ? (_Float16)1.f : (_Float16)0.f;
        a3[i] = (((pkB >> (16 + 2 * i)) & 3) == 1) ? (_Float16)1.f : (_Float16)0.f;
      }
      acc[0][0] = __builtin_amdgcn_mfma_f32_16x16x32_f16(a0, b00, acc[0][0], 0, 0, 0);
      acc[0][1] = __builtin_amdgcn_mfma_f32_16x16x32_f16(a0, b01, acc[0][1], 0, 0, 0);
      acc[1][0] = __builtin_amdgcn_mfma_f32_16x16x32_f16(a1, b00, acc[1][0], 0, 0, 0);
      acc[1][1] = __builtin_amdgcn_mfma_f32_16x16x32_f16(a1, b01, acc[1][1], 0, 0, 0);
      acc[2][0] = __builtin_amdgcn_mfma_f32_16x16x32_f16(a2, b00, acc[2][0], 0, 0, 0);
      acc[2][1] = __builtin_amdgcn_mfma_f32_16x16x32_f16(a2, b01, acc[2][1], 0, 0, 0);
      acc[3][0] = __builtin_amdgcn_mfma_f32_16x16x32_f16(a3, b00, acc[3][0], 0, 0, 0);
      acc[3][1] = __builtin_amdgcn_mfma_f32_16x16x32_f16(a3, b01, acc[3][1], 0, 0, 0);
    }
    // channel 2
    {
      half8 a0, a1, a2, a3;
#pragma unroll
      for (int i = 0; i < 8; ++i) {
        a0[i] = (((pkA >> (2 * i)) & 3) == 2) ? (_Float16)1.f : (_Float16)0.f;
        a1[i] = (((pkA >> (16 + 2 * i)) & 3) == 2) ? (_Float16)1.f : (_Float16)0.f;
        a2[i] = (((pkB >> (2 * i)) & 3) == 2) ? (_Float16)1.f : (_Float16)0.f;
        a3[i] = (((pkB >> (16 + 2 * i)) & 3) == 2) ? (_Float16)1.f : (_Float16)0.f;
      }
      acc[0][0] = __builtin_amdgcn_mfma_f32_16x16x32_f16(a0, b10, acc[0][0], 0, 0, 0);
      acc[0][1] = __builtin_amdgcn_mfma_f32_16x16x32_f16(a0, b11, acc[0][1], 0, 0, 0);
      acc[1][0] = __builtin_amdgcn_mfma_f32_16x16x32_f16(a1, b10, acc[1][0], 0, 0, 0);
      acc[1][1] = __builtin_amdgcn_mfma_f32_16x16x32_f16(a1, b11, acc[1][1], 0, 0, 0);
      acc[2][0] = __builtin_amdgcn_mfma_f32_16x16x32_f16(a2, b10, acc[2][0], 0, 0, 0);
      acc[2][1] = __builtin_amdgcn_mfma_f32_16x16x32_f16(a2, b11, acc[2][1], 0, 0, 0);
      acc[3][0] = __builtin_amdgcn_mfma_f32_16x16x32_f16(a3, b10, acc[3][0], 0, 0, 0);
      acc[3][1] = __builtin_amdgcn_mfma_f32_16x16x32_f16(a3, b11, acc[3][1], 0, 0, 0);
    }
    // channel 3
    {
      half8 a0, a1, a2, a3;
#pragma unroll
      for (int i = 0; i < 8; ++i) {
        a0[i] = (((pkA >> (2 * i)) & 3) == 3) ? (_Float16)1.f : (_Float16)0.f;
        a1[i] = (((pkA >> (16 + 2 * i)) & 3) == 3) ? (_Float16)1.f : (_Float16)0.f;
        a2[i] = (((pkB >> (2 * i)) & 3) == 3) ? (_Float16)1.f : (_Float16)0.f;
        a3[i] = (((pkB >> (16 + 2 * i)) & 3) == 3) ? (_Float16)1.f : (_Float16)0.f;
      }
      acc[0][0] = __builtin_amdgcn_mfma_f32_16x16x32_f16(a0, b20, acc[0][0], 0, 0, 0);
      acc[0][1] = __builtin_amdgcn_mfma_f32_16x16x32_f16(a0, b21, acc[0][1], 0, 0, 0);
      acc[1][0] = __builtin_amdgcn_mfma_f32_16x16x32_f16(a1, b20, acc[1][0], 0, 0, 0);
      acc[1][1] = __builtin_amdgcn_mfma_f32_16x16x32_f16(a1, b21, acc[1][1], 0, 0, 0);
      acc[2][0] = __builtin_amdgcn_mfma_f32_16x16x32_f16(a2, b20, acc[2][0], 0, 0, 0);
      acc[2][1] = __builtin_amdgcn_mfma_f32_16x16x32_f16(a2, b21, acc[2][1], 0, 0, 0);
      acc[3][0] = __builtin_amdgcn_mfma_f32_16x16x32_f16(a3, b20, acc[3][0], 0, 0, 0);
      acc[3][1] = __builtin_amdgcn_mfma_f32_16x16x32_f16(a3, b21, acc[3][1], 0, 0, 0);
    }
    if (tl < 7) {
      b00 = n00; b01 = n01; b10 = n10; b11 = n11; b20 = n20; b21 = n21;
    }
  }
  // cross-wave reduce: wave g handles row-group g (parallel epilogue)
#pragma unroll
  for (int g = 0; g < 4; ++g)
#pragma unroll
    for (int h = 0; h < 2; ++h)
#pragma unroll
      for (int r = 0; r < 4; ++r) red[w][g * 2 + h][lane][r] = acc[g][h][r];
  __syncthreads();
  {
    const int rbase = rg * 64 + w * 16;  // this wave's row-group
#pragma unroll
    for (int h = 0; h < 2; ++h) {
#pragma unroll
      for (int r = 0; r < 4; ++r) {
        const float v = red[0][w * 2 + h][lane][r] + red[1][w * 2 + h][lane][r] +
                        red[2][w * 2 + h][lane][r] + red[3][w * 2 + h][lane][r];
        // C/D: col = m (n-half h), row = q*4+r within the 16-row group
        Zpart[((size_t)c * NN + rbase + q * 4 + r) * 32 + h * 16 + m] = v;
      }
    }
  }
}

// ---------------------------------------------------------------------------
// pool_kernel: partials = per-block column sums of relu(sum_{c<8} Zpart + b)
// Grid 32 x 256: block owns 256 rows.
// ---------------------------------------------------------------------------
__global__ __launch_bounds__(256) void pool_kernel(
    const float* __restrict__ Zpart, const float* __restrict__ bias,
    float* __restrict__ partials) {
  const int tid = threadIdx.x;
  const int col = tid & 31, ro = tid >> 5;
  const float b = bias[col];
  float s = 0.f;
  for (int rr = 0; rr < 32; ++rr) {
    const size_t r = (size_t)blockIdx.x * 256 + ro * 32 + rr;
    float v = b;
#pragma unroll
    for (int c = 0; c < 8; ++c) v += Zpart[(size_t)c * NN * 32 + r * 32 + col];
    s += v > 0.f ? v : 0.f;
  }
  __shared__ float red[8][32];
  red[ro][col] = s;
  __syncthreads();
  if (tid < 32) {
    float t = 0.f;
#pragma unroll
    for (int i = 0; i < 8; ++i) t += red[i][tid];
    partials[(size_t)blockIdx.x * 32 + tid] = t;
  }
}

// ---------------------------------------------------------------------------
// fc_kernel: reduce pooled partials (np x 32), fc0+relu, fc1, sigmoid
// ---------------------------------------------------------------------------
__global__ __launch_bounds__(256) void fc_kernel(
    const float* __restrict__ partials, int np, const float* __restrict__ W0,
    const float* __restrict__ b0, const float* __restrict__ W1,
    const float* __restrict__ b1, float* __restrict__ out) {
  __shared__ float acc8[8][32];
  __shared__ float z[32], y[32];
  const int tid = threadIdx.x;
  const int col = tid & 31, ch = tid >> 5;
  float s = 0.f;
  for (int i = ch; i < np; i += 8) s += partials[(size_t)i * 32 + col];
  acc8[ch][col] = s;
  __syncthreads();
  if (tid < 32) {
    float t = 0.f;
#pragma unroll
    for (int i = 0; i < 8; ++i) t += acc8[i][tid];
    z[tid] = t;
  }
  __syncthreads();
  if (tid < 32) {
    float acc = b0[tid];
    for (int n = 0; n < 32; ++n) acc += W0[tid * 32 + n] * z[n];
    y[tid] = acc > 0.f ? acc : 0.f;
  }
  __syncthreads();
  if (tid == 0) {
    float acc = b1[0];
    for (int mm = 0; mm < 32; ++mm) acc += W1[mm] * y[mm];
    out[0] = 1.f / (1.f + expf(-acc));
  }
}

extern "C" void kernel_launch(void* const* d_in, const int* in_sizes, int n_in,
                              void* d_out, int out_size, void* d_ws,
                              size_t ws_size, hipStream_t stream) {
  const float* V   = (const float*)d_in[0];
  const int*   adj = (const int*)d_in[1];
  const float *w10 = (const float*)d_in[2], *w20 = (const float*)d_in[3],
              *w30 = (const float*)d_in[4], *gb0 = (const float*)d_in[5];
  const float *w11 = (const float*)d_in[6], *w21 = (const float*)d_in[7],
              *w31 = (const float*)d_in[8], *gb1 = (const float*)d_in[9];
  const float *fW0 = (const float*)d_in[10], *fb0 = (const float*)d_in[11],
              *fW1 = (const float*)d_in[12], *fb1 = (const float*)d_in[13];
  float* out = (float*)d_out;
  char* ws = (char*)d_ws;

  _Float16* Hfrag    = (_Float16*)ws;                 // 1,572,864 B
  float*    Zpart    = (float*)(ws + 1572864);        // 8,388,608 B
  float*    partials = (float*)(ws + 9961472);        //   262,144 B
  uint*     packed   = (uint*)(ws + 10223616);        // 16,777,216 B

  pack_kernel<<<2048, 256, 0, stream>>>(adj, packed);
  h_kernel<0><<<dim3(128, 3), 256, 0, stream>>>(V, w10, w20, w30, nullptr,
                                                Hfrag);
  agg_kernel<<<1024, 256, 0, stream>>>(packed, (const half8*)Hfrag, Zpart);
  h_kernel<1><<<dim3(128, 3), 256, 0, stream>>>(Zpart, w11, w21, w31, gb0,
                                                Hfrag);
  agg_kernel<<<1024, 256, 0, stream>>>(packed, (const half8*)Hfrag, Zpart);
  pool_kernel<<<32, 256, 0, stream>>>(Zpart, gb1, partials);
  fc_kernel<<<1, 256, 0, stream>>>(partials, 32, fW0, fb0, fW1, fb1, out);
}